// Round 3
// baseline (4088.113 us; speedup 1.0000x reference)
//
#include <hip/hip_runtime.h>

// Problem constants
#define NBATCH 16
#define HWD    128          // H == W == 128
#define HW2    16384        // 128*128 tokens per batch
#define EMB    512
#define NHEADS 8
#define HDIM   64
#define NWIN   256          // 16x16 windows
#define TOK    64           // tokens per window (8x8)
#define SHIFTV 4
#define PADW   68           // LDS row stride in floats (16B aligned, odd in float4 units)

// -------------------------------------------------------------------------
// Kernel 1: per (batch, window, head) fused QKV + softmax + PV.
// The -shift cyclic roll is folded into the global load addressing; the
// raw-reshape + +shift roll is folded into the store addressing, so the
// output workspace rows are already in final spatial order for the proj GEMM.
// -------------------------------------------------------------------------
__global__ __launch_bounds__(256, 2)
void attn_kernel(const float* __restrict__ x,
                 const float* __restrict__ Wqkv,   // [192][64] row-major
                 const float* __restrict__ bqkv,   // [192]
                 float* __restrict__ o_ws)         // [16][16384][512]
{
    __shared__ float Xs[TOK * PADW];   // X tile, reused as P (scores/probs)
    __shared__ float Qs[TOK * PADW];
    __shared__ float Ks[TOK * PADW];
    __shared__ float Vs[TOK * PADW];

    const int tid = threadIdx.x;
    const int bid = blockIdx.x;
    const int n   = bid & 7;            // head
    const int wd  = (bid >> 3) & 255;   // window
    const int b   = bid >> 11;          // batch

    const int lane = tid & 63;
    const int wid  = __builtin_amdgcn_readfirstlane(tid >> 6);  // wave id 0..3

    // ---- Phase 0: load X tile [64 tokens][64 dims] with -shift roll ----
    {
        const int tl = tid >> 2;          // token 0..63
        const int q  = tid & 3;           // 16-float quarter of the row
        const int i  = tl >> 3, j = tl & 7;
        const int wh = wd >> 4, ww = wd & 15;
        const int hs = (wh * 8 + i + SHIFTV) & 127;
        const int ws = (ww * 8 + j + SHIFTV) & 127;
        const float* src = x + (size_t)(b * HW2 + hs * HWD + ws) * EMB + n * HDIM + q * 16;
        float* dst = &Xs[tl * PADW + q * 16];
        #pragma unroll
        for (int v = 0; v < 4; ++v)
            *(float4*)(dst + v * 4) = *(const float4*)(src + v * 4);
    }
    __syncthreads();

    // ---- Phase 1: QKV.  thread = (token lane, wave) ; wave owns 48 of 192 outs ----
    {
        float xr[64];
        #pragma unroll
        for (int c4 = 0; c4 < 16; ++c4) {
            float4 v = *(const float4*)&Xs[lane * PADW + c4 * 4];
            xr[c4*4+0] = v.x; xr[c4*4+1] = v.y; xr[c4*4+2] = v.z; xr[c4*4+3] = v.w;
        }
        const int dbase = wid * 48;
        for (int d4 = 0; d4 < 12; ++d4) {
            float a[4];
            #pragma unroll
            for (int s = 0; s < 4; ++s) {
                const int d = dbase + d4 * 4 + s;       // wave-uniform -> s_loads
                const float* wr = Wqkv + d * HDIM;
                float acc = bqkv[d];
                #pragma unroll
                for (int c = 0; c < 64; ++c)
                    acc = fmaf(xr[c], wr[c], acc);
                a[s] = acc;
            }
            const int d0 = dbase + d4 * 4;
            float4 val = make_float4(a[0], a[1], a[2], a[3]);
            if (d0 < 64) {          // Q (pre-scaled by 1/sqrt(64))
                val.x *= 0.125f; val.y *= 0.125f; val.z *= 0.125f; val.w *= 0.125f;
                *(float4*)&Qs[lane * PADW + d0] = val;
            } else if (d0 < 128) {  // K
                *(float4*)&Ks[lane * PADW + (d0 - 64)] = val;
            } else {                // V
                *(float4*)&Vs[lane * PADW + (d0 - 128)] = val;
            }
        }
    }
    __syncthreads();

    // ---- Phase 2: scores  P[t][u] = Q[t] . K[u]  (wave owns a 16-wide u block) ----
    {
        float qr[64];
        #pragma unroll
        for (int c4 = 0; c4 < 16; ++c4) {
            float4 v = *(const float4*)&Qs[lane * PADW + c4 * 4];
            qr[c4*4+0] = v.x; qr[c4*4+1] = v.y; qr[c4*4+2] = v.z; qr[c4*4+3] = v.w;
        }
        float p[16];
        #pragma unroll
        for (int uu = 0; uu < 16; ++uu) {
            const int u = wid * 16 + uu;
            float acc = 0.f;
            #pragma unroll
            for (int c4 = 0; c4 < 16; ++c4) {
                float4 kv = *(const float4*)&Ks[u * PADW + c4 * 4];
                acc = fmaf(qr[c4*4+0], kv.x, acc);
                acc = fmaf(qr[c4*4+1], kv.y, acc);
                acc = fmaf(qr[c4*4+2], kv.z, acc);
                acc = fmaf(qr[c4*4+3], kv.w, acc);
            }
            p[uu] = acc;
        }
        #pragma unroll
        for (int u4 = 0; u4 < 4; ++u4)
            *(float4*)&Xs[lane * PADW + wid * 16 + u4 * 4] =
                make_float4(p[u4*4], p[u4*4+1], p[u4*4+2], p[u4*4+3]);
    }
    __syncthreads();

    // ---- Softmax over u (4 threads per row, shfl_xor(1),(2) reductions) ----
    {
        const int tr = tid >> 2;
        const int q4 = tid & 3;
        float sp[16];
        #pragma unroll
        for (int i4 = 0; i4 < 4; ++i4) {
            float4 v = *(const float4*)&Xs[tr * PADW + q4 * 16 + i4 * 4];
            sp[i4*4+0] = v.x; sp[i4*4+1] = v.y; sp[i4*4+2] = v.z; sp[i4*4+3] = v.w;
        }
        float m = sp[0];
        #pragma unroll
        for (int i = 1; i < 16; ++i) m = fmaxf(m, sp[i]);
        m = fmaxf(m, __shfl_xor(m, 1));
        m = fmaxf(m, __shfl_xor(m, 2));
        float s = 0.f;
        #pragma unroll
        for (int i = 0; i < 16; ++i) { sp[i] = __expf(sp[i] - m); s += sp[i]; }
        s += __shfl_xor(s, 1);
        s += __shfl_xor(s, 2);
        const float inv = 1.0f / s;
        #pragma unroll
        for (int i4 = 0; i4 < 4; ++i4)
            *(float4*)&Xs[tr * PADW + q4 * 16 + i4 * 4] =
                make_float4(sp[i4*4]*inv, sp[i4*4+1]*inv, sp[i4*4+2]*inv, sp[i4*4+3]*inv);
    }
    __syncthreads();

    // ---- Phase 3: O = P.V ; store with raw-reshape + (+shift) roll ----
    {
        float pr[64];
        #pragma unroll
        for (int c4 = 0; c4 < 16; ++c4) {
            float4 v = *(const float4*)&Xs[lane * PADW + c4 * 4];
            pr[c4*4+0] = v.x; pr[c4*4+1] = v.y; pr[c4*4+2] = v.z; pr[c4*4+3] = v.w;
        }
        float o[16];
        #pragma unroll
        for (int i = 0; i < 16; ++i) o[i] = 0.f;
        const int d0 = wid * 16;
        #pragma unroll
        for (int u = 0; u < 64; ++u) {
            const float pu = pr[u];
            #pragma unroll
            for (int i4 = 0; i4 < 4; ++i4) {
                float4 vv = *(const float4*)&Vs[u * PADW + d0 + i4 * 4];
                o[i4*4+0] = fmaf(pu, vv.x, o[i4*4+0]);
                o[i4*4+1] = fmaf(pu, vv.y, o[i4*4+1]);
                o[i4*4+2] = fmaf(pu, vv.z, o[i4*4+2]);
                o[i4*4+3] = fmaf(pu, vv.w, o[i4*4+3]);
            }
        }
        // out2 row l = wd*64 + t ; h' = l>>7, w' = l&127 ; roll +shift
        const int l   = wd * 64 + lane;
        const int hp  = l >> 7, wp = l & 127;
        const int hpp = (hp + SHIFTV) & 127;
        const int wpp = (wp + SHIFTV) & 127;
        float* dst = o_ws + (size_t)(b * HW2 + hpp * HWD + wpp) * EMB + n * HDIM + d0;
        #pragma unroll
        for (int i4 = 0; i4 < 4; ++i4)
            *(float4*)(dst + i4 * 4) =
                make_float4(o[i4*4], o[i4*4+1], o[i4*4+2], o[i4*4+3]);
    }
}

// -------------------------------------------------------------------------
// Kernel 2: y = A * Wp^T + bp.  A = o_ws [262144 x 512], Wp [512 x 512].
// 128x128 tile, BK=16, 256 threads, 8x8 micro-tile per thread.
// -------------------------------------------------------------------------
__global__ __launch_bounds__(256)
void proj_kernel(const float* __restrict__ A,
                 const float* __restrict__ Wp,
                 const float* __restrict__ bp,
                 float* __restrict__ y)
{
    __shared__ float As[16 * 132];   // [k][row], padded
    __shared__ float Bs[16 * 132];   // [k][col], padded

    const int tid  = threadIdx.x;
    const int colT = blockIdx.x & 3;
    const int rowT = blockIdx.x >> 2;
    const int tm = tid & 15, tn = tid >> 4;
    const int m0 = tm * 8, n0 = tn * 8;

    const int lr = tid >> 1;           // tile row/col 0..127
    const int lk = (tid & 1) * 8;      // k offset 0 or 8

    const float* Arow = A  + (size_t)(rowT * 128 + lr) * 512;
    const float* Wrow = Wp + (size_t)(colT * 128 + lr) * 512;

    float acc[8][8];
    #pragma unroll
    for (int i = 0; i < 8; ++i)
        #pragma unroll
        for (int j = 0; j < 8; ++j) acc[i][j] = 0.f;

    for (int k0 = 0; k0 < 512; k0 += 16) {
        float4 a0 = *(const float4*)(Arow + k0 + lk);
        float4 a1 = *(const float4*)(Arow + k0 + lk + 4);
        float4 w0 = *(const float4*)(Wrow + k0 + lk);
        float4 w1 = *(const float4*)(Wrow + k0 + lk + 4);
        __syncthreads();
        As[(lk+0)*132 + lr] = a0.x; As[(lk+1)*132 + lr] = a0.y;
        As[(lk+2)*132 + lr] = a0.z; As[(lk+3)*132 + lr] = a0.w;
        As[(lk+4)*132 + lr] = a1.x; As[(lk+5)*132 + lr] = a1.y;
        As[(lk+6)*132 + lr] = a1.z; As[(lk+7)*132 + lr] = a1.w;
        Bs[(lk+0)*132 + lr] = w0.x; Bs[(lk+1)*132 + lr] = w0.y;
        Bs[(lk+2)*132 + lr] = w0.z; Bs[(lk+3)*132 + lr] = w0.w;
        Bs[(lk+4)*132 + lr] = w1.x; Bs[(lk+5)*132 + lr] = w1.y;
        Bs[(lk+6)*132 + lr] = w1.z; Bs[(lk+7)*132 + lr] = w1.w;
        __syncthreads();
        #pragma unroll
        for (int k = 0; k < 16; ++k) {
            float ar[8], br[8];
            float4 t0 = *(const float4*)&As[k*132 + m0];
            float4 t1 = *(const float4*)&As[k*132 + m0 + 4];
            ar[0]=t0.x; ar[1]=t0.y; ar[2]=t0.z; ar[3]=t0.w;
            ar[4]=t1.x; ar[5]=t1.y; ar[6]=t1.z; ar[7]=t1.w;
            float4 u0 = *(const float4*)&Bs[k*132 + n0];
            float4 u1 = *(const float4*)&Bs[k*132 + n0 + 4];
            br[0]=u0.x; br[1]=u0.y; br[2]=u0.z; br[3]=u0.w;
            br[4]=u1.x; br[5]=u1.y; br[6]=u1.z; br[7]=u1.w;
            #pragma unroll
            for (int i = 0; i < 8; ++i)
                #pragma unroll
                for (int j = 0; j < 8; ++j)
                    acc[i][j] = fmaf(ar[i], br[j], acc[i][j]);
        }
    }

    const float4 bb0 = *(const float4*)(bp + colT*128 + n0);
    const float4 bb1 = *(const float4*)(bp + colT*128 + n0 + 4);
    #pragma unroll
    for (int i = 0; i < 8; ++i) {
        float* dst = y + (size_t)(rowT * 128 + m0 + i) * 512 + colT * 128 + n0;
        *(float4*)(dst)     = make_float4(acc[i][0]+bb0.x, acc[i][1]+bb0.y,
                                          acc[i][2]+bb0.z, acc[i][3]+bb0.w);
        *(float4*)(dst + 4) = make_float4(acc[i][4]+bb1.x, acc[i][5]+bb1.y,
                                          acc[i][6]+bb1.z, acc[i][7]+bb1.w);
    }
}

extern "C" void kernel_launch(void* const* d_in, const int* in_sizes, int n_in,
                              void* d_out, int out_size, void* d_ws, size_t ws_size,
                              hipStream_t stream) {
    const float* x    = (const float*)d_in[0];
    const float* Wqkv = (const float*)d_in[1];
    const float* bqkv = (const float*)d_in[2];
    const float* Wp   = (const float*)d_in[3];
    const float* bp   = (const float*)d_in[4];
    float* y  = (float*)d_out;
    float* ws = (float*)d_ws;

    const size_t need = (size_t)NBATCH * HW2 * EMB * sizeof(float);  // 512 MiB
    if (ws_size < need) return;  // workspace too small: fail loudly via validation

    // Kernel 1: 16 batches * 256 windows * 8 heads = 32768 blocks
    attn_kernel<<<NBATCH * NWIN * NHEADS, 256, 0, stream>>>(x, Wqkv, bqkv, ws);
    // Kernel 2: (262144/128) row tiles * (512/128) col tiles = 8192 blocks
    proj_kernel<<<(NBATCH * HW2 / 128) * (EMB / 128), 256, 0, stream>>>(ws, Wp, bp, y);
}

// Round 6
// 1538.571 us; speedup vs baseline: 2.6571x; 2.6571x over previous
//
#include <hip/hip_runtime.h>

// Problem constants
#define NBATCH 16
#define HWD    128
#define HW2    16384
#define EMB    512
#define NHEADS 8
#define HDIM   64
#define NWIN   256
#define TOK    64
#define SHIFTV 4
#define LPAD   72            // LDS row stride in bf16 elems (144 B = 16 mod 128 -> uniform bank slots)

typedef __attribute__((ext_vector_type(8))) short bf16x8;
typedef __attribute__((ext_vector_type(4))) float f32x4;

__device__ __forceinline__ unsigned short f2bf(float f) {
    union { float f; unsigned u; } v; v.f = f;
    unsigned r = v.u + 0x7fffu + ((v.u >> 16) & 1u);   // RNE
    return (unsigned short)(r >> 16);
}

// -------------------------------------------------------------------------
// Kernel 0: one-time fp32 -> bf16 conversion of W_qkv [192*64] and W_proj
// [512*512] into workspace.
// -------------------------------------------------------------------------
__global__ void cvt_weights(const float* __restrict__ wq, const float* __restrict__ wp,
                            unsigned short* __restrict__ wq_bf, unsigned short* __restrict__ wp_bf) {
    int i = blockIdx.x * 256 + threadIdx.x;
    if (i < 192 * 64)   wq_bf[i] = f2bf(wq[i]);
    if (i < 512 * 512)  wp_bf[i] = f2bf(wp[i]);
}

// -------------------------------------------------------------------------
// Kernel 1: per (batch, window, head) fused QKV + softmax + PV, bf16 MFMA.
// Shift roll folded into load; raw-reshape + reverse roll folded into store.
// MFMA fragment conventions (16x16x32 bf16):
//   A[i][k]: i = lane&15, k = (lane>>4)*8 + j   (8 contiguous k per lane)
//   B[k][j]: j = lane&15, k = (lane>>4)*8 + j
//   C[i][j]: j = lane&15, i = (lane>>4)*4 + reg
// -------------------------------------------------------------------------
__global__ __launch_bounds__(256, 2)
void attn_kernel(const float* __restrict__ x,
                 const unsigned short* __restrict__ wq_bf,  // [192][64] bf16
                 const float* __restrict__ bqkv,            // [192] f32
                 unsigned short* __restrict__ o_ws)         // [16][16384][512] bf16
{
    __shared__ unsigned short Xs[TOK * LPAD];   // X head slice [tok][d]
    __shared__ unsigned short Ws[192 * LPAD];   // W_qkv [d'][d]
    __shared__ unsigned short Qs[TOK * LPAD];   // Q [tok][d]  (pre-scaled)
    __shared__ unsigned short Ks[TOK * LPAD];   // K [tok][d]
    __shared__ unsigned short Vs[TOK * LPAD];   // V TRANSPOSED [d][tok]
    __shared__ unsigned short Ps[TOK * LPAD];   // P [tok][u]

    const int tid  = threadIdx.x;
    const int bid  = blockIdx.x;
    const int n    = bid & 7;
    const int wd   = (bid >> 3) & 255;
    const int b    = bid >> 11;
    const int lane = tid & 63;
    const int w    = tid >> 6;          // wave 0..3
    const int lr   = lane & 15;
    const int lg   = lane >> 4;

    // ---- Phase 0: X head slice -> bf16 LDS (shift roll folded); W_qkv -> LDS ----
    {
        const int tl = tid >> 2;             // token 0..63
        const int q  = tid & 3;              // 16-col quarter
        const int i  = tl >> 3, j = tl & 7;
        const int wh = wd >> 4, ww = wd & 15;
        const int hs = (wh * 8 + i + SHIFTV) & 127;
        const int ws_ = (ww * 8 + j + SHIFTV) & 127;
        const float* src = x + (size_t)(b * HW2 + hs * HWD + ws_) * EMB + n * HDIM + q * 16;
        float4 f0 = *(const float4*)(src + 0);
        float4 f1 = *(const float4*)(src + 4);
        float4 f2 = *(const float4*)(src + 8);
        float4 f3 = *(const float4*)(src + 12);
        bf16x8 s0, s1;
        s0[0]=(short)f2bf(f0.x); s0[1]=(short)f2bf(f0.y); s0[2]=(short)f2bf(f0.z); s0[3]=(short)f2bf(f0.w);
        s0[4]=(short)f2bf(f1.x); s0[5]=(short)f2bf(f1.y); s0[6]=(short)f2bf(f1.z); s0[7]=(short)f2bf(f1.w);
        s1[0]=(short)f2bf(f2.x); s1[1]=(short)f2bf(f2.y); s1[2]=(short)f2bf(f2.z); s1[3]=(short)f2bf(f2.w);
        s1[4]=(short)f2bf(f3.x); s1[5]=(short)f2bf(f3.y); s1[6]=(short)f2bf(f3.z); s1[7]=(short)f2bf(f3.w);
        *(bf16x8*)&Xs[tl * LPAD + q * 16]     = s0;
        *(bf16x8*)&Xs[tl * LPAD + q * 16 + 8] = s1;
        // W_qkv: 192*64 bf16 = 1536 chunks of 8
        for (int c = tid; c < 192 * 8; c += 256) {
            const int row = c >> 3, c8 = (c & 7) * 8;
            bf16x8 v = *(const bf16x8*)(wq_bf + row * 64 + c8);
            *(bf16x8*)&Ws[row * LPAD + c8] = v;
        }
    }
    __syncthreads();

    // ---- Phase 1: QKV GEMM [64tok x 192] = Xs[64x64] . Ws^T ----
    {
        bf16x8 afrag[4][2];
        #pragma unroll
        for (int mt = 0; mt < 4; ++mt)
            #pragma unroll
            for (int kt = 0; kt < 2; ++kt)
                afrag[mt][kt] = *(const bf16x8*)&Xs[(mt * 16 + lr) * LPAD + kt * 32 + lg * 8];

        #pragma unroll
        for (int ntl = 0; ntl < 3; ++ntl) {
            const int nt = w * 3 + ntl;          // 0..11
            const int d0 = nt * 16;
            f32x4 acc[4];
            #pragma unroll
            for (int mt = 0; mt < 4; ++mt) acc[mt] = f32x4{0.f, 0.f, 0.f, 0.f};
            #pragma unroll
            for (int kt = 0; kt < 2; ++kt) {
                bf16x8 bfr = *(const bf16x8*)&Ws[(d0 + lr) * LPAD + kt * 32 + lg * 8];
                #pragma unroll
                for (int mt = 0; mt < 4; ++mt)
                    acc[mt] = __builtin_amdgcn_mfma_f32_16x16x32_bf16(afrag[mt][kt], bfr, acc[mt], 0, 0, 0);
            }
            const int dcol = d0 + lr;            // 0..191
            const float bias = bqkv[dcol];
            unsigned short* dst;
            float scale = 1.0f;
            int cc;
            bool isV = false;
            if (dcol < 64)        { dst = Qs; cc = dcol;       scale = 0.125f; }
            else if (dcol < 128)  { dst = Ks; cc = dcol - 64; }
            else                  { dst = Vs; cc = dcol - 128; isV = true; }
            #pragma unroll
            for (int mt = 0; mt < 4; ++mt)
                #pragma unroll
                for (int r = 0; r < 4; ++r) {
                    const float vv = (acc[mt][r] + bias) * scale;
                    const int t = mt * 16 + lg * 4 + r;
                    if (isV) dst[cc * LPAD + t] = f2bf(vv);   // V transposed [d][tok]
                    else     dst[t * LPAD + cc] = f2bf(vv);
                }
        }
    }
    __syncthreads();

    // ---- Phase 2: S = Q.K^T (wave w owns rows 16w..16w+15) + f32 softmax ----
    {
        bf16x8 aq[2];
        #pragma unroll
        for (int kt = 0; kt < 2; ++kt)
            aq[kt] = *(const bf16x8*)&Qs[(w * 16 + lr) * LPAD + kt * 32 + lg * 8];
        f32x4 s[4];
        #pragma unroll
        for (int nt = 0; nt < 4; ++nt) {
            s[nt] = f32x4{0.f, 0.f, 0.f, 0.f};
            #pragma unroll
            for (int kt = 0; kt < 2; ++kt) {
                bf16x8 bk = *(const bf16x8*)&Ks[(nt * 16 + lr) * LPAD + kt * 32 + lg * 8];
                s[nt] = __builtin_amdgcn_mfma_f32_16x16x32_bf16(aq[kt], bk, s[nt], 0, 0, 0);
            }
        }
        // softmax per row (row = 16w + 4*lg + r); cols u = nt*16 + lr spread over 16 lanes
        #pragma unroll
        for (int r = 0; r < 4; ++r) {
            float m = fmaxf(fmaxf(s[0][r], s[1][r]), fmaxf(s[2][r], s[3][r]));
            m = fmaxf(m, __shfl_xor(m, 1));
            m = fmaxf(m, __shfl_xor(m, 2));
            m = fmaxf(m, __shfl_xor(m, 4));
            m = fmaxf(m, __shfl_xor(m, 8));
            float e0 = __expf(s[0][r] - m);
            float e1 = __expf(s[1][r] - m);
            float e2 = __expf(s[2][r] - m);
            float e3 = __expf(s[3][r] - m);
            float sum = e0 + e1 + e2 + e3;
            sum += __shfl_xor(sum, 1);
            sum += __shfl_xor(sum, 2);
            sum += __shfl_xor(sum, 4);
            sum += __shfl_xor(sum, 8);
            const float inv = 1.0f / sum;
            const int row = (w * 16 + lg * 4 + r) * LPAD;
            Ps[row + 0 * 16 + lr] = f2bf(e0 * inv);
            Ps[row + 1 * 16 + lr] = f2bf(e1 * inv);
            Ps[row + 2 * 16 + lr] = f2bf(e2 * inv);
            Ps[row + 3 * 16 + lr] = f2bf(e3 * inv);
        }
    }
    __syncthreads();

    // ---- Phase 3: O = P.V (wave w owns rows 16w..); store bf16 with +shift roll ----
    {
        bf16x8 ap[2];
        #pragma unroll
        for (int kt = 0; kt < 2; ++kt)
            ap[kt] = *(const bf16x8*)&Ps[(w * 16 + lr) * LPAD + kt * 32 + lg * 8];
        f32x4 o[4];
        #pragma unroll
        for (int nt = 0; nt < 4; ++nt) {
            o[nt] = f32x4{0.f, 0.f, 0.f, 0.f};
            #pragma unroll
            for (int kt = 0; kt < 2; ++kt) {
                bf16x8 bv = *(const bf16x8*)&Vs[(nt * 16 + lr) * LPAD + kt * 32 + lg * 8];
                o[nt] = __builtin_amdgcn_mfma_f32_16x16x32_bf16(ap[kt], bv, o[nt], 0, 0, 0);
            }
        }
        #pragma unroll
        for (int r = 0; r < 4; ++r) {
            const int t   = w * 16 + lg * 4 + r;
            const int l   = wd * 64 + t;
            const int hp  = l >> 7, wp = l & 127;
            const int hpp = (hp + SHIFTV) & 127;
            const int wpp = (wp + SHIFTV) & 127;
            unsigned short* dst = o_ws + (size_t)(b * HW2 + hpp * HWD + wpp) * EMB + n * HDIM;
            #pragma unroll
            for (int nt = 0; nt < 4; ++nt)
                dst[nt * 16 + lr] = f2bf(o[nt][r]);
        }
    }
}

// -------------------------------------------------------------------------
// Kernel 2: y = A(bf16) . Wp^T(bf16) + bp, fp32 out. 128x128 tile, BK=64,
// 4 waves in 2x2, each 64x64 via 16x16x32 MFMA.
// -------------------------------------------------------------------------
__global__ __launch_bounds__(256)
void proj_kernel(const unsigned short* __restrict__ A,    // [262144][512] bf16
                 const unsigned short* __restrict__ Wb,   // [512][512] bf16
                 const float* __restrict__ bp,
                 float* __restrict__ y)
{
    __shared__ unsigned short As[128 * LPAD];
    __shared__ unsigned short Bs[128 * LPAD];

    const int tid  = threadIdx.x;
    const int colT = blockIdx.x & 3;
    const int rowT = blockIdx.x >> 2;
    const int lane = tid & 63;
    const int w    = tid >> 6;
    const int lr   = lane & 15;
    const int lg   = lane >> 4;
    const int wy   = w >> 1, wx = w & 1;       // 2x2 wave grid

    f32x4 acc[4][4];
    #pragma unroll
    for (int mt = 0; mt < 4; ++mt)
        #pragma unroll
        for (int nt = 0; nt < 4; ++nt) acc[mt][nt] = f32x4{0.f, 0.f, 0.f, 0.f};

    const size_t arow0 = (size_t)rowT * 128;
    const size_t brow0 = (size_t)colT * 128;

    for (int k0 = 0; k0 < 512; k0 += 64) {
        __syncthreads();
        for (int c = tid; c < 1024; c += 256) {          // 128 rows x 8 chunks
            const int r = c >> 3, c8 = (c & 7) * 8;
            bf16x8 va = *(const bf16x8*)(A  + (arow0 + r) * 512 + k0 + c8);
            *(bf16x8*)&As[r * LPAD + c8] = va;
            bf16x8 vb = *(const bf16x8*)(Wb + (brow0 + r) * 512 + k0 + c8);
            *(bf16x8*)&Bs[r * LPAD + c8] = vb;
        }
        __syncthreads();
        #pragma unroll
        for (int kt = 0; kt < 2; ++kt) {
            bf16x8 af[4], bfv[4];
            #pragma unroll
            for (int mt = 0; mt < 4; ++mt)
                af[mt] = *(const bf16x8*)&As[(wy * 64 + mt * 16 + lr) * LPAD + kt * 32 + lg * 8];
            #pragma unroll
            for (int nt = 0; nt < 4; ++nt)
                bfv[nt] = *(const bf16x8*)&Bs[(wx * 64 + nt * 16 + lr) * LPAD + kt * 32 + lg * 8];
            #pragma unroll
            for (int mt = 0; mt < 4; ++mt)
                #pragma unroll
                for (int nt = 0; nt < 4; ++nt)
                    acc[mt][nt] = __builtin_amdgcn_mfma_f32_16x16x32_bf16(af[mt], bfv[nt], acc[mt][nt], 0, 0, 0);
        }
    }

    #pragma unroll
    for (int nt = 0; nt < 4; ++nt) {
        const int f = colT * 128 + wx * 64 + nt * 16 + lr;
        const float bias = bp[f];
        #pragma unroll
        for (int mt = 0; mt < 4; ++mt) {
            const size_t mrow = arow0 + wy * 64 + mt * 16 + lg * 4;
            #pragma unroll
            for (int r = 0; r < 4; ++r)
                y[(mrow + r) * 512 + f] = acc[mt][nt][r] + bias;
        }
    }
}

extern "C" void kernel_launch(void* const* d_in, const int* in_sizes, int n_in,
                              void* d_out, int out_size, void* d_ws, size_t ws_size,
                              hipStream_t stream) {
    const float* x    = (const float*)d_in[0];
    const float* Wqkv = (const float*)d_in[1];
    const float* bqkv = (const float*)d_in[2];
    const float* Wp   = (const float*)d_in[3];
    const float* bp   = (const float*)d_in[4];
    float* y = (float*)d_out;

    // ws layout: o_bf [16*16384*512 bf16] = 268435456 B; wq_bf 24576 B; wp_bf 524288 B
    unsigned short* o_bf  = (unsigned short*)d_ws;
    unsigned short* wq_bf = (unsigned short*)((char*)d_ws + 268435456u);
    unsigned short* wp_bf = (unsigned short*)((char*)d_ws + 268435456u + 24576u);
    const size_t need = 268435456u + 24576u + 524288u;
    if (ws_size < need) return;

    cvt_weights<<<1024, 256, 0, stream>>>(Wqkv, Wp, wq_bf, wp_bf);
    attn_kernel<<<NBATCH * NWIN * NHEADS, 256, 0, stream>>>(x, wq_bf, bqkv, o_bf);
    proj_kernel<<<(NBATCH * HW2 / 128) * (EMB / 128), 256, 0, stream>>>(o_bf, wp_bf, bp, y);
}